// Round 1
// baseline (1412.827 us; speedup 1.0000x reference)
//
#include <hip/hip_runtime.h>

// Deconw: depthwise transposed conv, stride 1, valid padding.
// x: (16,128,512,64) f32 NHWC ; W: (4,10,64) f32 ; b: (64,) f32
// out: (16,64,131,521) f32 (NCHW, trailing singleton dim dropped)
// y[b,c,oh,ow] = bias[c] + sum_{p<4,q<10, 0<=oh-p<128, 0<=ow-q<512} x[b,oh-p,ow-q,c]*W[p,q,c]

#define H_IN 128
#define W_IN 512
#define C_CH 64
#define KH 4
#define KW 10
#define OHT 131
#define OWT 521
#define OW_TILE 64
#define OH_TILE 16
#define LSTRIDE 81   // LDS row stride in floats (81 mod 32 = 17, odd -> 2-way max)
#define NW_STRIPS 9  // ceil(521/64)
#define NH_STRIPS 9  // ceil(131/16)

// ---- stage row IH of global x into stg[5] (float4 each; coalesced, OOB->0) ----
#define STAGE(IH)                                                          \
  {                                                                        \
    const int rowb = ((bN * H_IN + (IH)) * W_IN);                          \
    _Pragma("unroll")                                                      \
    for (int k = 0; k < 5; ++k) {                                          \
      const int f   = tid + 256 * k;                                       \
      const int iwl = f >> 4;                                              \
      const int c4  = f & 15;                                              \
      const int iw  = w0 - (KW - 1) + iwl;                                 \
      if (iw >= 0 && iw < W_IN)                                            \
        stg[k] = xf4[(rowb + iw) * (C_CH / 4) + c4];                       \
      else                                                                 \
        stg[k] = make_float4(0.f, 0.f, 0.f, 0.f);                          \
    }                                                                      \
  }

// ---- scatter staged regs into LDS transposed layout [c][iw] ----
#define LDSWRITE(IH)                                                       \
  {                                                                        \
    float* Lb = lbuf[(IH) & 1];                                            \
    _Pragma("unroll")                                                      \
    for (int k = 0; k < 5; ++k) {                                          \
      const int f   = tid + 256 * k;                                       \
      const int iwl = f >> 4;                                              \
      const int c4  = (f & 15) * 4;                                        \
      Lb[(c4 + 0) * LSTRIDE + iwl] = stg[k].x;                             \
      Lb[(c4 + 1) * LSTRIDE + iwl] = stg[k].y;                             \
      Lb[(c4 + 2) * LSTRIDE + iwl] = stg[k].z;                             \
      Lb[(c4 + 3) * LSTRIDE + iwl] = stg[k].w;                             \
    }                                                                      \
  }

// ---- 25-float window from LDS, 640 FMAs into the 4 rolling rows ----
#define COMPUTE(IH, A0_, A1_, A2_, A3_)                                    \
  {                                                                        \
    const float* Lb = lbuf[(IH) & 1];                                      \
    float xv[25];                                                          \
    _Pragma("unroll")                                                      \
    for (int t = 0; t < 25; ++t) xv[t] = Lb[c * LSTRIDE + ws * 16 + t];    \
    _Pragma("unroll")                                                      \
    for (int q = 0; q < KW; ++q) {                                         \
      const float w0_ = wk[q];                                             \
      const float w1_ = wk[KW + q];                                        \
      const float w2_ = wk[2 * KW + q];                                    \
      const float w3_ = wk[3 * KW + q];                                    \
      _Pragma("unroll")                                                    \
      for (int s = 0; s < 16; ++s) {                                       \
        const float xvv = xv[s + (KW - 1) - q];                            \
        A0_[s] = fmaf(xvv, w0_, A0_[s]);                                   \
        A1_[s] = fmaf(xvv, w1_, A1_[s]);                                   \
        A2_[s] = fmaf(xvv, w2_, A2_[s]);                                   \
        A3_[s] = fmaf(xvv, w3_, A3_[s]);                                   \
      }                                                                    \
    }                                                                      \
  }

// ---- write completed output row oh=IH (if in this block's range), reinit ----
#define EMIT(IH, A0_)                                                      \
  {                                                                        \
    const int oh = (IH);                                                   \
    if (oh >= oh0 && oh <= ohMax) {                                        \
      float* orow = outg + ((bN * C_CH + c) * OHT + oh) * OWT + owBase;    \
      if (owBase + 15 < OWT) {                                             \
        _Pragma("unroll")                                                  \
        for (int s = 0; s < 16; ++s) orow[s] = A0_[s];                     \
      } else {                                                             \
        _Pragma("unroll")                                                  \
        for (int s = 0; s < 16; ++s)                                       \
          if (owBase + s < OWT) orow[s] = A0_[s];                          \
      }                                                                    \
    }                                                                      \
    _Pragma("unroll")                                                      \
    for (int s = 0; s < 16; ++s) A0_[s] = biasv;                           \
  }

// One row-step. Single barrier per step: double-buffered LDS means the buffer
// written pre-barrier (buf[ih&1]) was last read two steps ago, which the
// previous step's barrier already ordered. Next row's global loads are issued
// right after the barrier so HBM latency hides under the 640 FMAs (T14).
#define STEP(A0_, A1_, A2_, A3_, IH)                                       \
  if ((IH) <= stepEnd) {                                                   \
    if ((IH) <= ihEnd) LDSWRITE(IH);                                       \
    __syncthreads();                                                       \
    if ((IH) + 1 <= ihEnd) STAGE((IH) + 1);                                \
    if ((IH) <= ihEnd) COMPUTE(IH, A0_, A1_, A2_, A3_);                    \
    EMIT(IH, A0_);                                                         \
  }

__global__ __launch_bounds__(256, 2) void deconw_kernel(
    const float* __restrict__ xg, const float* __restrict__ wg,
    const float* __restrict__ bg, float* __restrict__ outg)
{
    __shared__ float lbuf[2][C_CH * LSTRIDE];  // 2 x 20.25 KB

    const int tid  = threadIdx.x;
    const int bid  = blockIdx.x;
    const int wsid = bid % NW_STRIPS;
    const int hsid = (bid / NW_STRIPS) % NH_STRIPS;
    const int bN   = bid / (NW_STRIPS * NH_STRIPS);

    const int w0  = wsid * OW_TILE;   // first output col of strip
    const int oh0 = hsid * OH_TILE;   // first output row of strip

    const int c      = tid >> 2;      // channel owned by this thread
    const int ws     = tid & 3;       // 16-col sub-strip
    const int owBase = w0 + ws * 16;

    // per-channel weights + bias (wave-uniform per 4-lane group; one-time)
    float wk[KH * KW];
#pragma unroll
    for (int i = 0; i < KH * KW; ++i) wk[i] = wg[i * C_CH + c];
    const float biasv = bg[c];

    const int ihStart = (oh0 - (KH - 1)) > 0 ? (oh0 - (KH - 1)) : 0;
    const int ihEnd   = (oh0 + OH_TILE - 1) < (H_IN - 1) ? (oh0 + OH_TILE - 1) : (H_IN - 1);
    const int stepEnd = ihEnd + (KH - 1);  // flush steps produce tail rows
    const int ohMax   = (oh0 + OH_TILE - 1) < (OHT - 1) ? (oh0 + OH_TILE - 1) : (OHT - 1);

    const float4* xf4 = (const float4*)xg;
    float4 stg[5];

    // rolling accumulators: at step ih, A0<->oh=ih, A1<->ih+1, A2<->ih+2, A3<->ih+3
    float R0[16], R1[16], R2[16], R3[16];
#pragma unroll
    for (int s = 0; s < 16; ++s) { R0[s] = biasv; R1[s] = biasv; R2[s] = biasv; R3[s] = biasv; }

    STAGE(ihStart);

    for (int ihb = ihStart; ihb <= stepEnd; ihb += 4) {
        STEP(R0, R1, R2, R3, ihb + 0);
        STEP(R1, R2, R3, R0, ihb + 1);
        STEP(R2, R3, R0, R1, ihb + 2);
        STEP(R3, R0, R1, R2, ihb + 3);
    }
}

extern "C" void kernel_launch(void* const* d_in, const int* in_sizes, int n_in,
                              void* d_out, int out_size, void* d_ws, size_t ws_size,
                              hipStream_t stream)
{
    const float* x = (const float*)d_in[0];
    const float* W = (const float*)d_in[1];
    const float* b = (const float*)d_in[2];
    float* out     = (float*)d_out;

    const int B = 16;
    dim3 grid(NW_STRIPS * NH_STRIPS * B);  // 1296 blocks
    dim3 block(256);
    deconw_kernel<<<grid, block, 0, stream>>>(x, W, b, out);
}